// Round 2
// baseline (992.567 us; speedup 1.0000x reference)
//
#include <hip/hip_runtime.h>

typedef unsigned short u16;
typedef unsigned int   u32;
typedef __bf16 bf16x8 __attribute__((ext_vector_type(8)));
typedef float  f32x4  __attribute__((ext_vector_type(4)));

// Problem constants: B=64, S=D=DK=DV=512
#define BATCH 64
#define SEQ   512
#define BSS   (64 * 512 * 512)   // 16,777,216 elements per output tensor
#define MTOT  (64 * 512)         // 32768 rows for projections

__device__ __forceinline__ u16 f2bf(float f) {
  u32 u = __builtin_bit_cast(u32, f);
  u += 0x7FFFu + ((u >> 16) & 1u);   // round-to-nearest-even
  return (u16)(u >> 16);
}

__device__ __forceinline__ void gl16(const void* g, void* l) {
  __builtin_amdgcn_global_load_lds(
      (__attribute__((address_space(1))) void*)g,
      (__attribute__((address_space(3))) void*)l,
      16, 0, 0);
}

// ---------------------------------------------------------------------------
// fp32 -> bf16 conversion for sent+pos in one launch, 8 elements/thread
__global__ __launch_bounds__(256) void cvt2_bf16_kernel(
    const float* __restrict__ in0, u16* __restrict__ out0,
    const float* __restrict__ in1, u16* __restrict__ out1, int n8) {
  int i = blockIdx.x * 256 + threadIdx.x;
  const float* in = in0;
  u16* out = out0;
  if (i >= n8) { i -= n8; in = in1; out = out1; }
  const float4* p = reinterpret_cast<const float4*>(in) + (size_t)i * 2;
  float4 x = p[0], y = p[1];
  uint4 r;
  r.x = (u32)f2bf(x.x) | ((u32)f2bf(x.y) << 16);
  r.y = (u32)f2bf(x.z) | ((u32)f2bf(x.w) << 16);
  r.z = (u32)f2bf(y.x) | ((u32)f2bf(y.y) << 16);
  r.w = (u32)f2bf(y.z) | ((u32)f2bf(y.w) << 16);
  reinterpret_cast<uint4*>(out)[i] = r;
}

// pack 5 weight matrices (each 512x512 row-major [out,in]) into bf16 concats
__global__ __launch_bounds__(256) void pack_w_kernel(
    const float* __restrict__ wq, const float* __restrict__ wk,
    const float* __restrict__ wv, const float* __restrict__ wpq,
    const float* __restrict__ wpk, u16* __restrict__ wc1, u16* __restrict__ wc2) {
  int i = blockIdx.x * 256 + threadIdx.x;        // 0 .. 5*262144-1
  int which = i >> 18;
  int off = i & 262143;
  const float* src = which == 0 ? wq : which == 1 ? wk : which == 2 ? wv
                   : which == 3 ? wpq : wpk;
  u16 h = f2bf(src[off]);
  if (which < 3) wc1[(size_t)which * 262144 + off] = h;
  else           wc2[(size_t)(which - 3) * 262144 + off] = h;
}

__global__ __launch_bounds__(256) void pack_bias_kernel(
    const float* __restrict__ bq, const float* __restrict__ bk,
    const float* __restrict__ bv, const float* __restrict__ bpq,
    const float* __restrict__ bpk, float* __restrict__ b1, float* __restrict__ b2) {
  int i = blockIdx.x * 256 + threadIdx.x;        // 0..2559
  if (i < 1536) {
    b1[i] = i < 512 ? bq[i] : i < 1024 ? bk[i - 512] : bv[i - 1024];
  } else {
    int j = i - 1536;
    b2[j] = j < 512 ? bpq[j] : bpk[j - 512];
  }
}

// ---------------------------------------------------------------------------
// NT GEMM for the projections (unchanged, verified in round 1).
// MODE 0: proj1 -> bf16, +bias, cols [0,1536) route to QU/KU/V
// MODE 1: proj2 -> bf16, +bias, cols [0,1024) route to QU+512/KU+512
template <int MODE>
__global__ __launch_bounds__(256) void gemm_nt(
    const u16* __restrict__ A, const u16* __restrict__ Bm, int K,
    u16* __restrict__ U0, u16* __restrict__ U1, u16* __restrict__ U2,
    const float* __restrict__ bias) {
  __shared__ u16 lsA[128 * 32];
  __shared__ u16 lsB[128 * 32];

  const int t = threadIdx.x;
  const int m0 = blockIdx.y * 128;
  const int n0 = blockIdx.x * 128;

  const int srow = t >> 2;
  const int scol = (t & 3) * 8;
  const u16* gA0 = A + (size_t)(m0 + srow) * K + scol;
  const u16* gB0 = Bm + (size_t)(n0 + srow) * K + scol;
  const size_t rowskip = (size_t)64 * K;
  u16* lA0 = lsA + t * 8;
  u16* lA1 = lsA + 2048 + t * 8;
  u16* lB0 = lsB + t * 8;
  u16* lB1 = lsB + 2048 + t * 8;

  const int l = t & 63;
  const int w = t >> 6;
  const int wm = (w & 1) * 64;
  const int wn = (w >> 1) * 64;
  const int fr = l & 15;
  const int fk = (l >> 4) * 8;

  f32x4 acc[4][4];
#pragma unroll
  for (int i = 0; i < 4; ++i)
#pragma unroll
    for (int j = 0; j < 4; ++j) acc[i][j] = (f32x4){0.f, 0.f, 0.f, 0.f};

  for (int k0 = 0; k0 < K; k0 += 32) {
    gl16(gA0 + k0, lA0);
    gl16(gA0 + rowskip + k0, lA1);
    gl16(gB0 + k0, lB0);
    gl16(gB0 + rowskip + k0, lB1);
    __syncthreads();
    bf16x8 af[4], bfg[4];
#pragma unroll
    for (int mt = 0; mt < 4; ++mt)
      af[mt] = *reinterpret_cast<const bf16x8*>(&lsA[(wm + mt * 16 + fr) * 32 + fk]);
#pragma unroll
    for (int nt = 0; nt < 4; ++nt)
      bfg[nt] = *reinterpret_cast<const bf16x8*>(&lsB[(wn + nt * 16 + fr) * 32 + fk]);
#pragma unroll
    for (int mt = 0; mt < 4; ++mt)
#pragma unroll
      for (int nt = 0; nt < 4; ++nt)
        acc[mt][nt] = __builtin_amdgcn_mfma_f32_16x16x32_bf16(
            af[mt], bfg[nt], acc[mt][nt], 0, 0, 0);
    __syncthreads();
  }

  const int cr = (l >> 4) * 4;
  const int cc = l & 15;
#pragma unroll
  for (int mt = 0; mt < 4; ++mt) {
#pragma unroll
    for (int nt = 0; nt < 4; ++nt) {
      const int col = n0 + wn + nt * 16 + cc;
#pragma unroll
      for (int r = 0; r < 4; ++r) {
        const int row = m0 + wm + mt * 16 + cr + r;
        float v = acc[mt][nt][r] + bias[col];
        u16 h = f2bf(v);
        const int which = col >> 9, c = col & 511;
        if (MODE == 0) {
          if (which == 0)      U0[(size_t)row * 1024 + c] = h;        // Q -> QU[:, :512]
          else if (which == 1) U1[(size_t)row * 1024 + c] = h;        // K -> KU[:, :512]
          else                 U2[(size_t)row * 512 + c] = h;         // V
        } else {
          if (which == 0) U0[(size_t)row * 1024 + 512 + c] = h;       // Uq -> QU[:, 512:]
          else            U1[(size_t)row * 1024 + 512 + c] = h;       // Uk -> KU[:, 512:]
        }
      }
    }
  }
}

// ---------------------------------------------------------------------------
// Fused score + softmax + PV.
// Block: one batch b, 64 Q-rows (rg), all 512 cols. 512 threads = 8 waves,
// wave w owns cols [w*64, w*64+64) as a 4x4 grid of 16x16x32 MFMA tiles.
// Phase 1: S = QU[rows] . KU^T (K=1024), scale + bias -> softmax in-regs
//          (shfl within 16-lane col groups + LDS cross-wave combine),
//          att fp32 -> d_out, P kept in acc registers.
// Phase 2: O = P . V^T in 16 t-steps of 32; owning wave spills its P-chunk
//          bf16 to padded LDS (stride 40 u16), V staged into lsB via gl16.
__global__ __launch_bounds__(512, 2) void fused_attn(
    const u16* __restrict__ QU, const u16* __restrict__ KU,
    const u16* __restrict__ Vb, const float* __restrict__ bias,
    float* __restrict__ attF, float* __restrict__ outO) {
  __shared__ u16 lsA[64 * 32];       // 4 KB  Q-tile (phase 1)
  __shared__ u16 lsB[512 * 32];      // 32 KB K-tile (phase 1) / V-tile (phase 2)
  __shared__ u16 lsP[64 * 40];       // 5 KB  P-chunk, padded stride 40
  __shared__ float sred[64 * 8];     // 2 KB  softmax cross-wave reduce

  const int t = threadIdx.x;
  const int b = blockIdx.x;          // batch  (id%8 == b%8 -> XCD locality)
  const int rg = blockIdx.y;         // row group (64 rows)
  const int l = t & 63;
  const int w = t >> 6;              // 0..7
  const int wn = w * 64;
  const int fr = l & 15;
  const int fk = (l >> 4) * 8;
  const int q = l >> 4;
  const int cc = l & 15;
  const int cr = q * 4;

  const u16* Aq = QU + ((size_t)(b * 512 + rg * 64)) * 1024;
  const u16* Bk = KU + ((size_t)b * 512) * 1024;

  // staging addresses (chunk = 16 B = 8 bf16)
  const u16* gA = Aq + (size_t)(t >> 2) * 1024 + (t & 3) * 8;   // t<256 only
  const u16* gB = Bk + (size_t)(t >> 2) * 1024 + (t & 3) * 8;   // + qq*128 rows

  float bc[4];
#pragma unroll
  for (int nt = 0; nt < 4; ++nt) bc[nt] = bias[wn + nt * 16 + cc];

  f32x4 acc[4][4];
#pragma unroll
  for (int i = 0; i < 4; ++i)
#pragma unroll
    for (int j = 0; j < 4; ++j) acc[i][j] = (f32x4){0.f, 0.f, 0.f, 0.f};

  // ---- phase 1: S = Q . K^T over K=1024 ----
  for (int k0 = 0; k0 < 1024; k0 += 32) {
    __syncthreads();
    if (t < 256) gl16(gA + k0, lsA + t * 8);
#pragma unroll
    for (int qq = 0; qq < 4; ++qq)
      gl16(gB + (size_t)qq * 128 * 1024 + k0, lsB + (qq * 512 + t) * 8);
    __syncthreads();
    bf16x8 af[4], bfg[4];
#pragma unroll
    for (int mt = 0; mt < 4; ++mt)
      af[mt] = *reinterpret_cast<const bf16x8*>(&lsA[(mt * 16 + fr) * 32 + fk]);
#pragma unroll
    for (int nt = 0; nt < 4; ++nt)
      bfg[nt] = *reinterpret_cast<const bf16x8*>(&lsB[(wn + nt * 16 + fr) * 32 + fk]);
#pragma unroll
    for (int mt = 0; mt < 4; ++mt)
#pragma unroll
      for (int nt = 0; nt < 4; ++nt)
        acc[mt][nt] = __builtin_amdgcn_mfma_f32_16x16x32_bf16(
            af[mt], bfg[nt], acc[mt][nt], 0, 0, 0);
  }

  // ---- scale + bias ----
#pragma unroll
  for (int mt = 0; mt < 4; ++mt)
#pragma unroll
    for (int nt = 0; nt < 4; ++nt)
#pragma unroll
      for (int r = 0; r < 4; ++r)
        acc[mt][nt][r] = acc[mt][nt][r] * 0.03125f + bc[nt];

  // ---- softmax: row max ----
  float pm[4][4];
#pragma unroll
  for (int mt = 0; mt < 4; ++mt)
#pragma unroll
    for (int r = 0; r < 4; ++r) {
      float m = fmaxf(fmaxf(acc[mt][0][r], acc[mt][1][r]),
                      fmaxf(acc[mt][2][r], acc[mt][3][r]));
#pragma unroll
      for (int s = 1; s < 16; s <<= 1) m = fmaxf(m, __shfl_xor(m, s, 64));
      pm[mt][r] = m;
    }
  if (cc == 0) {
#pragma unroll
    for (int mt = 0; mt < 4; ++mt)
#pragma unroll
      for (int r = 0; r < 4; ++r)
        sred[(mt * 16 + cr + r) * 8 + w] = pm[mt][r];
  }
  __syncthreads();
  float rowm[4][4];
#pragma unroll
  for (int mt = 0; mt < 4; ++mt)
#pragma unroll
    for (int r = 0; r < 4; ++r) {
      const float* p = &sred[(mt * 16 + cr + r) * 8];
      f32x4 a = *reinterpret_cast<const f32x4*>(p);
      f32x4 c = *reinterpret_cast<const f32x4*>(p + 4);
      rowm[mt][r] = fmaxf(fmaxf(fmaxf(a[0], a[1]), fmaxf(a[2], a[3])),
                          fmaxf(fmaxf(c[0], c[1]), fmaxf(c[2], c[3])));
    }
  __syncthreads();

  // ---- softmax: exp + row sum ----
#pragma unroll
  for (int mt = 0; mt < 4; ++mt)
#pragma unroll
    for (int r = 0; r < 4; ++r) {
      float s = 0.f;
#pragma unroll
      for (int nt = 0; nt < 4; ++nt) {
        float e = __expf(acc[mt][nt][r] - rowm[mt][r]);
        acc[mt][nt][r] = e;
        s += e;
      }
#pragma unroll
      for (int sh = 1; sh < 16; sh <<= 1) s += __shfl_xor(s, sh, 64);
      pm[mt][r] = s;
    }
  if (cc == 0) {
#pragma unroll
    for (int mt = 0; mt < 4; ++mt)
#pragma unroll
      for (int r = 0; r < 4; ++r)
        sred[(mt * 16 + cr + r) * 8 + w] = pm[mt][r];
  }
  __syncthreads();
#pragma unroll
  for (int mt = 0; mt < 4; ++mt)
#pragma unroll
    for (int r = 0; r < 4; ++r) {
      const float* p = &sred[(mt * 16 + cr + r) * 8];
      f32x4 a = *reinterpret_cast<const f32x4*>(p);
      f32x4 c = *reinterpret_cast<const f32x4*>(p + 4);
      float s = (a[0] + a[1]) + (a[2] + a[3]) + (c[0] + c[1]) + (c[2] + c[3]);
      rowm[mt][r] = 1.0f / s;
    }

  // ---- normalize + write att fp32 (output 0); P stays in acc ----
  float* attBase = attF + (size_t)b * 262144 + (size_t)rg * 64 * 512;
#pragma unroll
  for (int mt = 0; mt < 4; ++mt)
#pragma unroll
    for (int nt = 0; nt < 4; ++nt)
#pragma unroll
      for (int r = 0; r < 4; ++r) {
        float a = acc[mt][nt][r] * rowm[mt][r];
        acc[mt][nt][r] = a;
        attBase[(size_t)(mt * 16 + cr + r) * 512 + wn + nt * 16 + cc] = a;
      }

  // ---- phase 2: O = P . V^T over t=512 in 16 steps of 32 ----
  f32x4 acc2[4][4];
#pragma unroll
  for (int i = 0; i < 4; ++i)
#pragma unroll
    for (int j = 0; j < 4; ++j) acc2[i][j] = (f32x4){0.f, 0.f, 0.f, 0.f};

  const u16* gV = Vb + (size_t)b * 262144 + (size_t)(t >> 2) * 512 + (t & 3) * 8;

  for (int ts = 0; ts < 16; ++ts) {
    __syncthreads();
#pragma unroll
    for (int qq = 0; qq < 4; ++qq)
      gl16(gV + (size_t)qq * 128 * 512 + ts * 32, lsB + (qq * 512 + t) * 8);
    if (w == (ts >> 1)) {
      const int h0 = (ts & 1) * 2;
#pragma unroll
      for (int mt = 0; mt < 4; ++mt)
#pragma unroll
        for (int hh = 0; hh < 2; ++hh)
#pragma unroll
          for (int r = 0; r < 4; ++r)
            lsP[(mt * 16 + cr + r) * 40 + hh * 16 + cc] =
                f2bf(acc[mt][h0 + hh][r]);
    }
    __syncthreads();
    bf16x8 pa[4], vbf[4];
#pragma unroll
    for (int mt = 0; mt < 4; ++mt)
      pa[mt] = *reinterpret_cast<const bf16x8*>(&lsP[(mt * 16 + fr) * 40 + fk]);
#pragma unroll
    for (int nt = 0; nt < 4; ++nt)
      vbf[nt] = *reinterpret_cast<const bf16x8*>(&lsB[(wn + nt * 16 + fr) * 32 + fk]);
#pragma unroll
    for (int mt = 0; mt < 4; ++mt)
#pragma unroll
      for (int nt = 0; nt < 4; ++nt)
        acc2[mt][nt] = __builtin_amdgcn_mfma_f32_16x16x32_bf16(
            pa[mt], vbf[nt], acc2[mt][nt], 0, 0, 0);
  }

  // ---- write O (output 1) ----
  float* oBase = outO + (size_t)b * 262144 + (size_t)rg * 64 * 512;
#pragma unroll
  for (int mt = 0; mt < 4; ++mt)
#pragma unroll
    for (int nt = 0; nt < 4; ++nt)
#pragma unroll
      for (int r = 0; r < 4; ++r)
        oBase[(size_t)(mt * 16 + cr + r) * 512 + wn + nt * 16 + cc] =
            acc2[mt][nt][r];
}

// ---------------------------------------------------------------------------
extern "C" void kernel_launch(void* const* d_in, const int* in_sizes, int n_in,
                              void* d_out, int out_size, void* d_ws,
                              size_t ws_size, hipStream_t stream) {
  const float* sent = (const float*)d_in[0];
  const float* pos  = (const float*)d_in[1];
  // d_in[2] = branch_emb (unused by reference)
  const float* Wq  = (const float*)d_in[3];
  const float* bq  = (const float*)d_in[4];
  const float* Wk  = (const float*)d_in[5];
  const float* bk  = (const float*)d_in[6];
  const float* Wv  = (const float*)d_in[7];
  const float* bv  = (const float*)d_in[8];
  const float* Wpq = (const float*)d_in[9];
  const float* bpq = (const float*)d_in[10];
  const float* Wpk = (const float*)d_in[11];
  const float* bpk = (const float*)d_in[12];
  const float* abias = (const float*)d_in[13];
  float* out = (float*)d_out;

  // ws layout (bytes)
  char* ws = (char*)d_ws;
  u16* Xs   = (u16*)(ws);                    // sent bf16 [32768,512]
  u16* Xp   = (u16*)(ws + 33554432ul);       // pos  bf16
  u16* QU   = (u16*)(ws + 67108864ul);       // [32768,1024] = Q|Uq
  u16* KU   = (u16*)(ws + 134217728ul);      // [32768,1024] = K|Uk
  u16* Vb   = (u16*)(ws + 201326592ul);      // [32768,512]
  u16* Wc1  = (u16*)(ws + 268435456ul);      // [1536,512]
  u16* Wc2  = (u16*)(ws + 270008320ul);      // [1024,512]
  float* b1 = (float*)(ws + 271056896ul);
  float* b2 = (float*)(ws + 271063040ul);

  float* attF = out;            // output 0: att_softmax
  float* out2 = out + BSS;      // output 1: bmm result

  cvt2_bf16_kernel<<<16384, 256, 0, stream>>>(sent, Xs, pos, Xp, MTOT * 512 / 8);
  pack_w_kernel<<<5120, 256, 0, stream>>>(Wq, Wk, Wv, Wpq, Wpk, Wc1, Wc2);
  pack_bias_kernel<<<10, 256, 0, stream>>>(bq, bk, bv, bpq, bpk, b1, b2);

  // projections: [32768,512] x [N,512]^T
  gemm_nt<0><<<dim3(12, 256, 1), 256, 0, stream>>>(Xs, Wc1, 512, QU, KU, Vb, b1);
  gemm_nt<1><<<dim3(8, 256, 1), 256, 0, stream>>>(Xp, Wc2, 512, QU, KU, nullptr, b2);

  // fused score + softmax + PV
  fused_attn<<<dim3(BATCH, 8, 1), 512, 0, stream>>>(QU, KU, Vb, abias, attF, out2);

  (void)in_sizes; (void)n_in; (void)out_size; (void)ws_size;
}

// Round 3
// 550.953 us; speedup vs baseline: 1.8015x; 1.8015x over previous
//
#include <hip/hip_runtime.h>

typedef unsigned short u16;
typedef unsigned int   u32;
typedef __bf16 bf16x8 __attribute__((ext_vector_type(8)));
typedef float  f32x4  __attribute__((ext_vector_type(4)));

// Problem constants: B=64, S=D=DK=DV=512
#define BATCH 64
#define SEQ   512
#define BSS   (64 * 512 * 512)   // 16,777,216 elements per output tensor
#define MTOT  (64 * 512)         // 32768 rows for projections

__device__ __forceinline__ u16 f2bf(float f) {
  u32 u = __builtin_bit_cast(u32, f);
  u += 0x7FFFu + ((u >> 16) & 1u);   // round-to-nearest-even
  return (u16)(u >> 16);
}

__device__ __forceinline__ void gl16(const void* g, void* l) {
  __builtin_amdgcn_global_load_lds(
      (__attribute__((address_space(1))) void*)g,
      (__attribute__((address_space(3))) void*)l,
      16, 0, 0);
}

// ---------------------------------------------------------------------------
// fp32 -> bf16 conversion for sent+pos in one launch, 8 elements/thread
__global__ __launch_bounds__(256) void cvt2_bf16_kernel(
    const float* __restrict__ in0, u16* __restrict__ out0,
    const float* __restrict__ in1, u16* __restrict__ out1, int n8) {
  int i = blockIdx.x * 256 + threadIdx.x;
  const float* in = in0;
  u16* out = out0;
  if (i >= n8) { i -= n8; in = in1; out = out1; }
  const float4* p = reinterpret_cast<const float4*>(in) + (size_t)i * 2;
  float4 x = p[0], y = p[1];
  uint4 r;
  r.x = (u32)f2bf(x.x) | ((u32)f2bf(x.y) << 16);
  r.y = (u32)f2bf(x.z) | ((u32)f2bf(x.w) << 16);
  r.z = (u32)f2bf(y.x) | ((u32)f2bf(y.y) << 16);
  r.w = (u32)f2bf(y.z) | ((u32)f2bf(y.w) << 16);
  reinterpret_cast<uint4*>(out)[i] = r;
}

// pack 5 weight matrices (each 512x512 row-major [out,in]) into bf16 concats
__global__ __launch_bounds__(256) void pack_w_kernel(
    const float* __restrict__ wq, const float* __restrict__ wk,
    const float* __restrict__ wv, const float* __restrict__ wpq,
    const float* __restrict__ wpk, u16* __restrict__ wc1, u16* __restrict__ wc2) {
  int i = blockIdx.x * 256 + threadIdx.x;        // 0 .. 5*262144-1
  int which = i >> 18;
  int off = i & 262143;
  const float* src = which == 0 ? wq : which == 1 ? wk : which == 2 ? wv
                   : which == 3 ? wpq : wpk;
  u16 h = f2bf(src[off]);
  if (which < 3) wc1[(size_t)which * 262144 + off] = h;
  else           wc2[(size_t)(which - 3) * 262144 + off] = h;
}

__global__ __launch_bounds__(256) void pack_bias_kernel(
    const float* __restrict__ bq, const float* __restrict__ bk,
    const float* __restrict__ bv, const float* __restrict__ bpq,
    const float* __restrict__ bpk, float* __restrict__ b1, float* __restrict__ b2) {
  int i = blockIdx.x * 256 + threadIdx.x;        // 0..2559
  if (i < 1536) {
    b1[i] = i < 512 ? bq[i] : i < 1024 ? bk[i - 512] : bv[i - 1024];
  } else {
    int j = i - 1536;
    b2[j] = j < 512 ? bpq[j] : bpk[j - 512];
  }
}

// ---------------------------------------------------------------------------
// NT GEMM, 256(M) x 128(N) tile, K=512, BK=32. 512 threads = 8 waves in a
// 4(M) x 2(N) wave grid; each wave 64x64 via 4x4 mfma_f32_16x16x32_bf16.
// Per K-iter: stage A 16KB + B 8KB (3 gl16/thread), 16 MFMA/wave.
// MODE 0: proj1 -> bf16 +bias, cols [0,1536) route to QU/KU/V
// MODE 1: proj2 -> bf16 +bias, cols [0,1024) route to QU+512/KU+512
// MODE 2: bmm   -> fp32 out, batched over z (att . V^T)
template <int MODE>
__global__ __launch_bounds__(512, 2) void gemm256(
    const u16* __restrict__ A, const u16* __restrict__ Bm,
    u16* __restrict__ U0, u16* __restrict__ U1, u16* __restrict__ U2,
    const float* __restrict__ bias, float* __restrict__ F) {
  __shared__ u16 lsA[256 * 32];   // 16 KB
  __shared__ u16 lsB[128 * 32];   // 8 KB

  const int t = threadIdx.x;
  const int z = blockIdx.z;
  const int m0 = blockIdx.y * 256;
  const int n0 = blockIdx.x * 128;
  const int K = 512;

  const u16* Ab = A + (MODE == 2 ? (size_t)z * 262144 : 0);
  const u16* Bb = Bm + (MODE == 2 ? (size_t)z * 262144 : 0);
  float* Fb = (MODE == 2) ? (F + (size_t)z * 262144) : F;

  const int srow = t >> 2;          // 0..127
  const int scol = (t & 3) * 8;
  const u16* gA = Ab + (size_t)(m0 + srow) * K + scol;
  const u16* gB = Bb + (size_t)(n0 + srow) * K + scol;
  const size_t rskip = (size_t)128 * K;
  u16* lA0 = lsA + t * 8;
  u16* lA1 = lsA + 4096 + t * 8;
  u16* lB0 = lsB + t * 8;

  const int l = t & 63;
  const int w = t >> 6;
  const int wm = (w & 3) * 64;      // 0..192
  const int wn = (w >> 2) * 64;     // 0..64
  const int fr = l & 15;
  const int fk = (l >> 4) * 8;

  f32x4 acc[4][4];
#pragma unroll
  for (int i = 0; i < 4; ++i)
#pragma unroll
    for (int j = 0; j < 4; ++j) acc[i][j] = (f32x4){0.f, 0.f, 0.f, 0.f};

  for (int k0 = 0; k0 < K; k0 += 32) {
    gl16(gA + k0, lA0);
    gl16(gA + rskip + k0, lA1);
    gl16(gB + k0, lB0);
    __syncthreads();
    bf16x8 af[4], bfg[4];
#pragma unroll
    for (int mt = 0; mt < 4; ++mt)
      af[mt] = *reinterpret_cast<const bf16x8*>(&lsA[(wm + mt * 16 + fr) * 32 + fk]);
#pragma unroll
    for (int nt = 0; nt < 4; ++nt)
      bfg[nt] = *reinterpret_cast<const bf16x8*>(&lsB[(wn + nt * 16 + fr) * 32 + fk]);
#pragma unroll
    for (int mt = 0; mt < 4; ++mt)
#pragma unroll
      for (int nt = 0; nt < 4; ++nt)
        acc[mt][nt] = __builtin_amdgcn_mfma_f32_16x16x32_bf16(
            af[mt], bfg[nt], acc[mt][nt], 0, 0, 0);
    __syncthreads();
  }

  // C/D layout: col = lane&15, row = (lane>>4)*4 + reg
  const int cr = (l >> 4) * 4;
  const int cc = l & 15;
#pragma unroll
  for (int mt = 0; mt < 4; ++mt) {
#pragma unroll
    for (int nt = 0; nt < 4; ++nt) {
      const int col = n0 + wn + nt * 16 + cc;
#pragma unroll
      for (int r = 0; r < 4; ++r) {
        const int row = m0 + wm + mt * 16 + cr + r;
        float v = acc[mt][nt][r];
        if (MODE == 2) {
          Fb[(size_t)row * 512 + col] = v;
        } else {
          v += bias[col];
          u16 h = f2bf(v);
          const int which = col >> 9, c = col & 511;
          if (MODE == 0) {
            if (which == 0)      U0[(size_t)row * 1024 + c] = h;      // Q
            else if (which == 1) U1[(size_t)row * 1024 + c] = h;      // K
            else                 U2[(size_t)row * 512 + c] = h;       // V
          } else {
            if (which == 0) U0[(size_t)row * 1024 + 512 + c] = h;     // Uq
            else            U1[(size_t)row * 1024 + 512 + c] = h;     // Uk
          }
        }
      }
    }
  }
}

// ---------------------------------------------------------------------------
// Fused score + softmax (NO PV phase — that spilled in round 2).
// Block: batch b, 64 Q-rows, all 512 cols. 512 threads = 8 waves; wave w owns
// cols [w*64, w*64+64). S = QU . KU^T over K=1024, scale+bias, softmax
// in-register (shfl within 16-lane groups + LDS cross-wave combine).
// Writes att fp32 (output 0) and att bf16 (bmm input). Logits never hit HBM.
__global__ __launch_bounds__(512, 2) void score_softmax(
    const u16* __restrict__ QU, const u16* __restrict__ KU,
    const float* __restrict__ bias, float* __restrict__ attF,
    u16* __restrict__ attB) {
  __shared__ u16 lsA[64 * 32];       // 4 KB  Q-tile
  __shared__ u16 lsB[512 * 32];      // 32 KB K-tile
  __shared__ float sred[64 * 8];     // 2 KB  cross-wave reduce

  const int t = threadIdx.x;
  const int b = blockIdx.x;          // batch; 8 rg-blocks of b share XCD b%8
  const int rg = blockIdx.y;
  const int l = t & 63;
  const int w = t >> 6;
  const int wn = w * 64;
  const int fr = l & 15;
  const int fk = (l >> 4) * 8;
  const int cc = l & 15;
  const int cr = (l >> 4) * 4;

  const u16* gA = QU + ((size_t)(b * 512 + rg * 64 + (t >> 2))) * 1024 + (t & 3) * 8;
  const u16* gB = KU + ((size_t)(b * 512 + (t >> 2))) * 1024 + (t & 3) * 8;

  float bc[4];
#pragma unroll
  for (int nt = 0; nt < 4; ++nt) bc[nt] = bias[wn + nt * 16 + cc];

  f32x4 acc[4][4];
#pragma unroll
  for (int i = 0; i < 4; ++i)
#pragma unroll
    for (int j = 0; j < 4; ++j) acc[i][j] = (f32x4){0.f, 0.f, 0.f, 0.f};

  for (int k0 = 0; k0 < 1024; k0 += 32) {
    if (t < 256) gl16(gA + k0, lsA + t * 8);
#pragma unroll
    for (int qq = 0; qq < 4; ++qq)
      gl16(gB + (size_t)qq * 128 * 1024 + k0, lsB + (qq * 512 + t) * 8);
    __syncthreads();
    bf16x8 af[4], bfg[4];
#pragma unroll
    for (int mt = 0; mt < 4; ++mt)
      af[mt] = *reinterpret_cast<const bf16x8*>(&lsA[(mt * 16 + fr) * 32 + fk]);
#pragma unroll
    for (int nt = 0; nt < 4; ++nt)
      bfg[nt] = *reinterpret_cast<const bf16x8*>(&lsB[(wn + nt * 16 + fr) * 32 + fk]);
#pragma unroll
    for (int mt = 0; mt < 4; ++mt)
#pragma unroll
      for (int nt = 0; nt < 4; ++nt)
        acc[mt][nt] = __builtin_amdgcn_mfma_f32_16x16x32_bf16(
            af[mt], bfg[nt], acc[mt][nt], 0, 0, 0);
    __syncthreads();
  }

  // scale + bias
#pragma unroll
  for (int mt = 0; mt < 4; ++mt)
#pragma unroll
    for (int nt = 0; nt < 4; ++nt)
#pragma unroll
      for (int r = 0; r < 4; ++r)
        acc[mt][nt][r] = acc[mt][nt][r] * 0.03125f + bc[nt];

  // row max: shfl within 16-lane col groups, LDS across the 8 waves
  float rm[4][4];
#pragma unroll
  for (int mt = 0; mt < 4; ++mt)
#pragma unroll
    for (int r = 0; r < 4; ++r) {
      float m = fmaxf(fmaxf(acc[mt][0][r], acc[mt][1][r]),
                      fmaxf(acc[mt][2][r], acc[mt][3][r]));
#pragma unroll
      for (int s = 1; s < 16; s <<= 1) m = fmaxf(m, __shfl_xor(m, s, 64));
      rm[mt][r] = m;
    }
  if (cc == 0) {
#pragma unroll
    for (int mt = 0; mt < 4; ++mt)
#pragma unroll
      for (int r = 0; r < 4; ++r)
        sred[(mt * 16 + cr + r) * 8 + w] = rm[mt][r];
  }
  __syncthreads();
#pragma unroll
  for (int mt = 0; mt < 4; ++mt)
#pragma unroll
    for (int r = 0; r < 4; ++r) {
      const float* p = &sred[(mt * 16 + cr + r) * 8];
      f32x4 a = *reinterpret_cast<const f32x4*>(p);
      f32x4 c = *reinterpret_cast<const f32x4*>(p + 4);
      rm[mt][r] = fmaxf(fmaxf(fmaxf(a[0], a[1]), fmaxf(a[2], a[3])),
                        fmaxf(fmaxf(c[0], c[1]), fmaxf(c[2], c[3])));
    }
  __syncthreads();

  // exp + row sum
  float rs[4][4];
#pragma unroll
  for (int mt = 0; mt < 4; ++mt)
#pragma unroll
    for (int r = 0; r < 4; ++r) {
      float s = 0.f;
#pragma unroll
      for (int nt = 0; nt < 4; ++nt) {
        float e = __expf(acc[mt][nt][r] - rm[mt][r]);
        acc[mt][nt][r] = e;
        s += e;
      }
#pragma unroll
      for (int sh = 1; sh < 16; sh <<= 1) s += __shfl_xor(s, sh, 64);
      rs[mt][r] = s;
    }
  if (cc == 0) {
#pragma unroll
    for (int mt = 0; mt < 4; ++mt)
#pragma unroll
      for (int r = 0; r < 4; ++r)
        sred[(mt * 16 + cr + r) * 8 + w] = rs[mt][r];
  }
  __syncthreads();
#pragma unroll
  for (int mt = 0; mt < 4; ++mt)
#pragma unroll
    for (int r = 0; r < 4; ++r) {
      const float* p = &sred[(mt * 16 + cr + r) * 8];
      f32x4 a = *reinterpret_cast<const f32x4*>(p);
      f32x4 c = *reinterpret_cast<const f32x4*>(p + 4);
      rs[mt][r] = 1.0f / ((a[0] + a[1]) + (a[2] + a[3]) +
                          (c[0] + c[1]) + (c[2] + c[3]));
    }

  // normalize + write fp32 att (output 0) and bf16 att (bmm input)
  float* aF = attF + (size_t)b * 262144 + (size_t)rg * 64 * 512;
  u16* aB = attB + (size_t)b * 262144 + (size_t)rg * 64 * 512;
#pragma unroll
  for (int mt = 0; mt < 4; ++mt)
#pragma unroll
    for (int nt = 0; nt < 4; ++nt)
#pragma unroll
      for (int r = 0; r < 4; ++r) {
        const size_t idx = (size_t)(mt * 16 + cr + r) * 512 + wn + nt * 16 + cc;
        float a = acc[mt][nt][r] * rs[mt][r];
        aF[idx] = a;
        aB[idx] = f2bf(a);
      }
}

// ---------------------------------------------------------------------------
extern "C" void kernel_launch(void* const* d_in, const int* in_sizes, int n_in,
                              void* d_out, int out_size, void* d_ws,
                              size_t ws_size, hipStream_t stream) {
  const float* sent = (const float*)d_in[0];
  const float* pos  = (const float*)d_in[1];
  // d_in[2] = branch_emb (unused by reference)
  const float* Wq  = (const float*)d_in[3];
  const float* bq  = (const float*)d_in[4];
  const float* Wk  = (const float*)d_in[5];
  const float* bk  = (const float*)d_in[6];
  const float* Wv  = (const float*)d_in[7];
  const float* bv  = (const float*)d_in[8];
  const float* Wpq = (const float*)d_in[9];
  const float* bpq = (const float*)d_in[10];
  const float* Wpk = (const float*)d_in[11];
  const float* bpk = (const float*)d_in[12];
  const float* abias = (const float*)d_in[13];
  float* out = (float*)d_out;

  // ws layout (bytes)
  char* ws = (char*)d_ws;
  u16* Xs   = (u16*)(ws);                    // sent bf16 [32768,512]
  u16* Xp   = (u16*)(ws + 33554432ul);       // pos  bf16
  u16* QU   = (u16*)(ws + 67108864ul);       // [32768,1024] = Q|Uq
  u16* KU   = (u16*)(ws + 134217728ul);      // [32768,1024] = K|Uk
  u16* Vb   = (u16*)(ws + 201326592ul);      // [32768,512]
  u16* attB = (u16*)(ws + 234881024ul);      // [64*512,512] bf16 att
  u16* Wc1  = (u16*)(ws + 268435456ul);      // [1536,512]
  u16* Wc2  = (u16*)(ws + 270008320ul);      // [1024,512]
  float* b1 = (float*)(ws + 271056896ul);
  float* b2 = (float*)(ws + 271063040ul);

  float* attF = out;            // output 0: att_softmax
  float* out2 = out + BSS;      // output 1: bmm result

  cvt2_bf16_kernel<<<16384, 256, 0, stream>>>(sent, Xs, pos, Xp, MTOT * 512 / 8);
  pack_w_kernel<<<5120, 256, 0, stream>>>(Wq, Wk, Wv, Wpq, Wpk, Wc1, Wc2);
  pack_bias_kernel<<<10, 256, 0, stream>>>(bq, bk, bv, bpq, bpk, b1, b2);

  // projections: [32768,512] x [N,512]^T, 256x128 tiles
  gemm256<0><<<dim3(12, 128, 1), 512, 0, stream>>>(Xs, Wc1, QU, KU, Vb, b1, nullptr);
  gemm256<1><<<dim3(8, 128, 1), 512, 0, stream>>>(Xp, Wc2, QU, KU, nullptr, b2, nullptr);

  // fused score + softmax (logits never materialized)
  score_softmax<<<dim3(BATCH, 8, 1), 512, 0, stream>>>(QU, KU, abias, attF, attB);

  // output: per batch att[512,512] x V[512,512]^T, 256x128 tiles
  gemm256<2><<<dim3(4, 2, BATCH), 512, 0, stream>>>(attB, Vb, nullptr, nullptr,
                                                    nullptr, nullptr, out2);

  (void)in_sizes; (void)n_in; (void)out_size; (void)ws_size;
}